// Round 6
// baseline (1012.981 us; speedup 1.0000x reference)
//
#include <hip/hip_runtime.h>
#include <cfloat>

#define B_SZ    4096
#define D_MOD   768
#define DICT    24576
#define K_TOP   64
#define CAND_CAP 256
#define MARGIN  0.04f   // >= 2 * max fp16-GEMM error (~6e-3) + headroom
#define THR_EMIT 2.0f   // emission floor; per-row 64th value is ~2.66 min over rows
#define CAP2    1024    // per-row emission capacity (expected ~560)
#define CAP_BLK 16      // per-row per-block LDS emission capacity (lambda~2.9)
#define NBIN    512     // histogram bins = key bits 24:16
#define CAPF    256     // per-feature bucket capacity (expected max ~40)

typedef __attribute__((ext_vector_type(8))) short short8;
typedef __attribute__((ext_vector_type(8))) _Float16 half8;
typedef __attribute__((ext_vector_type(4))) float floatx4;

// ---------------------------------------------------------------------------
// helpers
// ---------------------------------------------------------------------------
__device__ __forceinline__ unsigned f2k(float f) {
  unsigned u = __float_as_uint(f);
  return (u & 0x80000000u) ? ~u : (u | 0x80000000u);
}
__device__ __forceinline__ float k2f(unsigned k) {
  unsigned u = (k & 0x80000000u) ? (k & 0x7FFFFFFFu) : ~k;
  return __uint_as_float(u);
}
__device__ __forceinline__ void gload_lds16(const void* g, void* l) {
  __builtin_amdgcn_global_load_lds(
      (const __attribute__((address_space(1))) unsigned*)g,
      (__attribute__((address_space(3))) unsigned*)l, 16, 0, 0);
}
__device__ __forceinline__ void cvt8(const float* __restrict__ S,
                                     short* __restrict__ D, int idx) {
  const float4* sp = (const float4*)S + (size_t)idx * 2;
  float4 a = sp[0], b = sp[1];
  half8 h;
  h[0] = (_Float16)a.x; h[1] = (_Float16)a.y;
  h[2] = (_Float16)a.z; h[3] = (_Float16)a.w;
  h[4] = (_Float16)b.x; h[5] = (_Float16)b.y;
  h[6] = (_Float16)b.z; h[7] = (_Float16)b.w;
  *((half8*)D + idx) = h;
}

// ---------------------------------------------------------------------------
// Kernel P: fused prep. Block roles:
//   [0, NB_CVT)                : fp32->fp16 convert of x then W_enc
//   [NB_CVT, +NB_TR)           : W_dec 32x32 tile transpose -> WdT
//   [NB_CVT+NB_TR, +B_SZ)      : zero one acts row each (402 MB streaming)
//   [.., +NB_META)             : zero ecnt/efail/fcnt/slow (grid-stride)
// ---------------------------------------------------------------------------
#define N8_X    (B_SZ * D_MOD / 8)
#define N8_ALL  ((B_SZ + DICT) * D_MOD / 8)
#define NB_CVT  (N8_ALL / 256)                 // 10752
#define NB_TR   ((DICT / 32) * (D_MOD / 32))   // 18432
#define NB_META 16
#define N_META  (3 * B_SZ + DICT)              // ecnt, efail, fcnt, slow (contiguous)
#define NB_PREP (NB_CVT + NB_TR + B_SZ + NB_META)

__global__ __launch_bounds__(256) void prep_kernel(
    const float* __restrict__ x, const float* __restrict__ W_enc,
    const float* __restrict__ Wd,
    short* __restrict__ Ah, short* __restrict__ Wh,
    float* __restrict__ WdT, float* __restrict__ acts,
    int* __restrict__ meta)   // = ecnt base; ecnt|efail|fcnt|slow contiguous
{
  __shared__ float tile[32][33];
  const int bid = blockIdx.x;
  const int tid = threadIdx.x;

  if (bid < NB_CVT) {
    int item = bid * 256 + tid;
    if (item < N8_X) cvt8(x, Ah, item);
    else             cvt8(W_enc, Wh, item - N8_X);
    return;
  }
  if (bid < NB_CVT + NB_TR) {
    const int t  = bid - NB_CVT;
    const int bx = t % (DICT / 32);
    const int by = t / (DICT / 32);
    const int tx = tid & 31, ty = tid >> 5;   // 32 x 8
    const int gx = bx * 32 + tx;
    const int y0 = by * 32;
    #pragma unroll
    for (int i = 0; i < 32; i += 8)
      tile[ty + i][tx] = Wd[(size_t)(y0 + ty + i) * DICT + gx];
    __syncthreads();
    const int xo = y0 + tx;
    const int yo = bx * 32;
    #pragma unroll
    for (int i = 0; i < 32; i += 8)
      WdT[(size_t)(yo + ty + i) * D_MOD + xo] = tile[tx][ty + i];
    return;
  }
  if (bid < NB_CVT + NB_TR + B_SZ) {
    const int row = bid - (NB_CVT + NB_TR);
    float4 z = {0.f, 0.f, 0.f, 0.f};
    float4* zp = (float4*)(acts + (size_t)row * DICT);
    #pragma unroll
    for (int c = 0; c < DICT / 4 / 256; ++c) zp[tid + 256 * c] = z;
    return;
  }
  // meta zero
  const int b = bid - (NB_CVT + NB_TR + B_SZ);
  for (int i = b * 256 + tid; i < N_META; i += NB_META * 256) meta[i] = 0;
}

// ---------------------------------------------------------------------------
// Kernel 0 (old-path only): fp32 -> fp16 convert
// ---------------------------------------------------------------------------
__global__ __launch_bounds__(256) void cvt_half(
    const float* __restrict__ S, short* __restrict__ D, int n8)
{
  int idx = blockIdx.x * 256 + threadIdx.x;
  if (idx >= n8) return;
  cvt8(S, D, idx);
}

// ---------------------------------------------------------------------------
// Kernel 1a: MFMA encoder GEMM (double-buffered prefetch) + LDS-aggregated
// candidate emission.
// ---------------------------------------------------------------------------
#define LOFF (128 * 32)   // shorts per LDS buffer

__global__ __launch_bounds__(256) void enc_gemm_emit(
    const short* __restrict__ Ah,   // [B_SZ, D_MOD] fp16 bits
    const short* __restrict__ Wh,   // [DICT, D_MOD] fp16 bits
    const float* __restrict__ bias,
    unsigned* __restrict__ epk,     // [B_SZ, CAP2]
    int* __restrict__ ecnt)         // [B_SZ]
{
  __shared__ __align__(16) short As[2][128][32];
  __shared__ __align__(16) short Bs[2][128][32];

  const int tid = threadIdx.x;
  const int l   = tid & 63;
  const int w   = tid >> 6;
  const int n0  = blockIdx.x * 128;
  const int m0  = blockIdx.y * 128;
  const int wr  = w >> 1, wc = w & 1;

  const int srow = (w * 2) * 16 + (l >> 2);
  const int kc   = (l & 3) * 8;
  const short* gA0 = Ah + (size_t)(m0 + srow) * D_MOD + kc;
  const short* gA1 = gA0 + (size_t)16 * D_MOD;
  const short* gB0 = Wh + (size_t)(n0 + srow) * D_MOD + kc;
  const short* gB1 = gB0 + (size_t)16 * D_MOD;
  short* lA0 = &As[0][(w * 2) * 16][0];
  short* lA1 = lA0 + 16 * 32;
  short* lB0 = &Bs[0][(w * 2) * 16][0];
  short* lB1 = lB0 + 16 * 32;

#define STAGE(buf, kt) do {                      \
    gload_lds16(gA0 + (kt), lA0 + (buf) * LOFF); \
    gload_lds16(gA1 + (kt), lA1 + (buf) * LOFF); \
    gload_lds16(gB0 + (kt), lB0 + (buf) * LOFF); \
    gload_lds16(gB1 + (kt), lB1 + (buf) * LOFF); \
  } while (0)

  floatx4 acc[4][4];
  #pragma unroll
  for (int i = 0; i < 4; ++i)
    #pragma unroll
    for (int j = 0; j < 4; ++j) acc[i][j] = (floatx4){0.f, 0.f, 0.f, 0.f};

  const int fr = l & 15;
  const int fq = (l >> 4) * 8;

  STAGE(0, 0);
  __syncthreads();                 // tile 0 landed
  int cur = 0;

  for (int kt = 32; kt <= D_MOD; kt += 32) {
    if (kt < D_MOD) STAGE(cur ^ 1, kt);   // prefetch next tile under compute
    half8 af[4], bf[4];
    #pragma unroll
    for (int t = 0; t < 4; ++t) {
      af[t] = *(const half8*)&As[cur][wr * 64 + t * 16 + fr][fq];
      bf[t] = *(const half8*)&Bs[cur][wc * 64 + t * 16 + fr][fq];
    }
    #pragma unroll
    for (int i = 0; i < 4; ++i)
      #pragma unroll
      for (int j = 0; j < 4; ++j)
        acc[i][j] = __builtin_amdgcn_mfma_f32_16x16x32_f16(af[i], bf[j], acc[i][j], 0, 0, 0);
    __syncthreads();               // drains vmcnt (prefetch) + lgkm
    cur ^= 1;
  }
#undef STAGE

  // ---- epilogue: LDS-aggregated emission ----
  unsigned* elist  = (unsigned*)&As[0][0][0];   // [128][CAP_BLK], 8 KB
  int*      ecnt_s = (int*)&Bs[0][0][0];        // [128]
  if (tid < 128) ecnt_s[tid] = 0;
  __syncthreads();

  // C/D layout: col = lane&15 (n), row = (lane>>4)*4 + reg (m)
  const int rq = (l >> 4) * 4;
  #pragma unroll
  for (int j = 0; j < 4; ++j) {
    const int n = n0 + wc * 64 + j * 16 + fr;
    const float bv = bias[n];
    #pragma unroll
    for (int i = 0; i < 4; ++i) {
      const int lr0 = wr * 64 + i * 16 + rq;   // local row base (0..127)
      #pragma unroll
      for (int r = 0; r < 4; ++r) {
        float v = acc[i][j][r] + bv;
        if (v > THR_EMIT) {
          const int lr = lr0 + r;
          unsigned ks = (v >= 32.f) ? 0x7FFFu : ((f2k(v) >> 10) & 0x7FFFu);
          int s = atomicAdd(&ecnt_s[lr], 1);
          if (s < CAP_BLK) elist[lr * CAP_BLK + s] = (ks << 15) | (unsigned)n;
          else atomicAdd(&ecnt[m0 + lr], CAP2 + 1);  // poison -> select fails -> fallback
        }
      }
    }
  }
  __syncthreads();

  if (tid < 128) {
    int c = ecnt_s[tid];
    if (c > 0) {
      if (c > CAP_BLK) c = CAP_BLK;
      const int row = m0 + tid;
      int base = atomicAdd(&ecnt[row], c);
      for (int s = 0; s < c; ++s) {
        int p = base + s;
        if (p < CAP2) epk[(size_t)row * CAP2 + p] = elist[tid * CAP_BLK + s];
      }
    }
  }
}

// ---------------------------------------------------------------------------
// Kernel 1a-old: MFMA GEMM writing dense C (fallback when ws lacks emit bufs)
// ---------------------------------------------------------------------------
__global__ __launch_bounds__(256) void enc_gemm_mfma(
    const short* __restrict__ Ah, const short* __restrict__ Wh,
    const float* __restrict__ bias, float* __restrict__ C)
{
  __shared__ short As[128][32];
  __shared__ short Bs[128][32];

  const int tid = threadIdx.x;
  const int l   = tid & 63;
  const int w   = tid >> 6;
  const int n0  = blockIdx.x * 128;
  const int m0  = blockIdx.y * 128;
  const int wr  = w >> 1, wc = w & 1;

  const int srow = (w * 2) * 16 + (l >> 2);
  const int kc   = (l & 3) * 8;
  const short* gA0 = Ah + (size_t)(m0 + srow) * D_MOD + kc;
  const short* gA1 = gA0 + (size_t)16 * D_MOD;
  const short* gB0 = Wh + (size_t)(n0 + srow) * D_MOD + kc;
  const short* gB1 = gB0 + (size_t)16 * D_MOD;
  short* lA0 = &As[(w * 2) * 16][0];
  short* lA1 = lA0 + 16 * 32;
  short* lB0 = &Bs[(w * 2) * 16][0];
  short* lB1 = lB0 + 16 * 32;

  floatx4 acc[4][4];
  #pragma unroll
  for (int i = 0; i < 4; ++i)
    #pragma unroll
    for (int j = 0; j < 4; ++j) acc[i][j] = (floatx4){0.f, 0.f, 0.f, 0.f};

  const int fr = l & 15;
  const int fq = (l >> 4) * 8;

  for (int kt = 0; kt < D_MOD; kt += 32) {
    __syncthreads();
    gload_lds16(gA0 + kt, lA0);
    gload_lds16(gA1 + kt, lA1);
    gload_lds16(gB0 + kt, lB0);
    gload_lds16(gB1 + kt, lB1);
    __syncthreads();
    half8 af[4], bf[4];
    #pragma unroll
    for (int t = 0; t < 4; ++t) {
      af[t] = *(const half8*)&As[wr * 64 + t * 16 + fr][fq];
      bf[t] = *(const half8*)&Bs[wc * 64 + t * 16 + fr][fq];
    }
    #pragma unroll
    for (int i = 0; i < 4; ++i)
      #pragma unroll
      for (int j = 0; j < 4; ++j)
        acc[i][j] = __builtin_amdgcn_mfma_f32_16x16x32_f16(af[i], bf[j], acc[i][j], 0, 0, 0);
  }

  const int rq = (l >> 4) * 4;
  #pragma unroll
  for (int j = 0; j < 4; ++j) {
    const int n = n0 + wc * 64 + j * 16 + fr;
    const float bv = bias[n];
    #pragma unroll
    for (int i = 0; i < 4; ++i) {
      const int mb = m0 + wr * 64 + i * 16 + rq;
      #pragma unroll
      for (int r = 0; r < 4; ++r)
        C[(size_t)(mb + r) * DICT + n] = acc[i][j][r] + bv;
    }
  }
}

// ---------------------------------------------------------------------------
// Kernel 1b (fallback, ws too small): fp32 VALU GEMM
// ---------------------------------------------------------------------------
#define BM 128
#define BN 128
#define BK 16
#define LDP (BM + 4)

__global__ __launch_bounds__(256) void enc_gemm(
    const float* __restrict__ A, const float* __restrict__ W,
    const float* __restrict__ bias, float* __restrict__ C)
{
  __shared__ float Asf[BK][LDP];
  __shared__ float Bsf[BK][LDP];

  const int tid = threadIdx.x;
  const int n0 = blockIdx.x * BN;
  const int m0 = blockIdx.y * BM;
  const int tx = tid & 15;
  const int ty = tid >> 4;
  const int lrow = tid >> 2;
  const int lc4  = tid & 3;

  const float* Aptr  = A + (size_t)(m0 + lrow) * D_MOD + lc4 * 4;
  const float* Aptr2 = Aptr + (size_t)64 * D_MOD;
  const float* Wptr  = W + (size_t)(n0 + lrow) * D_MOD + lc4 * 4;
  const float* Wptr2 = Wptr + (size_t)64 * D_MOD;

  float acc[8][8];
  #pragma unroll
  for (int i = 0; i < 8; ++i)
    #pragma unroll
    for (int j = 0; j < 8; ++j) acc[i][j] = 0.f;

  for (int kt = 0; kt < D_MOD; kt += BK) {
    float4 a0 = *(const float4*)(Aptr  + kt);
    float4 a1 = *(const float4*)(Aptr2 + kt);
    float4 b0 = *(const float4*)(Wptr  + kt);
    float4 b1 = *(const float4*)(Wptr2 + kt);
    __syncthreads();
    Asf[lc4*4+0][lrow] = a0.x;  Asf[lc4*4+1][lrow] = a0.y;
    Asf[lc4*4+2][lrow] = a0.z;  Asf[lc4*4+3][lrow] = a0.w;
    Asf[lc4*4+0][64+lrow] = a1.x;  Asf[lc4*4+1][64+lrow] = a1.y;
    Asf[lc4*4+2][64+lrow] = a1.z;  Asf[lc4*4+3][64+lrow] = a1.w;
    Bsf[lc4*4+0][lrow] = b0.x;  Bsf[lc4*4+1][lrow] = b0.y;
    Bsf[lc4*4+2][lrow] = b0.z;  Bsf[lc4*4+3][lrow] = b0.w;
    Bsf[lc4*4+0][64+lrow] = b1.x;  Bsf[lc4*4+1][64+lrow] = b1.y;
    Bsf[lc4*4+2][64+lrow] = b1.z;  Bsf[lc4*4+3][64+lrow] = b1.w;
    __syncthreads();
    #pragma unroll
    for (int k = 0; k < BK; ++k) {
      float a[8], b[8];
      *(float4*)&a[0] = *(const float4*)&Asf[k][ty*4];
      *(float4*)&a[4] = *(const float4*)&Asf[k][64 + ty*4];
      *(float4*)&b[0] = *(const float4*)&Bsf[k][tx*4];
      *(float4*)&b[4] = *(const float4*)&Bsf[k][64 + tx*4];
      #pragma unroll
      for (int i = 0; i < 8; ++i)
        #pragma unroll
        for (int j = 0; j < 8; ++j) acc[i][j] += a[i] * b[j];
    }
  }

  float4 bs0 = *(const float4*)(bias + n0 + tx*4);
  float4 bs1 = *(const float4*)(bias + n0 + 64 + tx*4);
  #pragma unroll
  for (int i = 0; i < 8; ++i) {
    int r = m0 + ((i < 4) ? (ty*4 + i) : (64 + ty*4 + i - 4));
    float* cp = C + (size_t)r * DICT + n0 + tx*4;
    float4 o0 = {acc[i][0]+bs0.x, acc[i][1]+bs0.y, acc[i][2]+bs0.z, acc[i][3]+bs0.w};
    float4 o1 = {acc[i][4]+bs1.x, acc[i][5]+bs1.y, acc[i][6]+bs1.z, acc[i][7]+bs1.w};
    *(float4*)cp = o0;
    *(float4*)(cp + 64) = o1;
  }
}

// ---------------------------------------------------------------------------
// Kernel S: per-row candidate selection + feature-bucket insertion.
// ---------------------------------------------------------------------------
__global__ __launch_bounds__(256) void select_kernel(
    const unsigned* __restrict__ epk, const int* __restrict__ ecnt,
    int* __restrict__ cand_idx, int* __restrict__ cand_cnt,
    int* __restrict__ efail, int* __restrict__ fcnt,
    int* __restrict__ fpair, int* __restrict__ slow)
{
  const int row = blockIdx.x;
  const int tid = threadIdx.x;
  __shared__ int hist[NBIN];
  __shared__ int cfeat_l[CAND_CAP];
  __shared__ int s_bb, s_out;

  const int cnt = ecnt[row];
  const int m   = (cnt < CAP2) ? cnt : CAP2;

  for (int i = tid; i < NBIN; i += 256) hist[i] = 0;
  if (tid == 0) { s_bb = -1; s_out = 0; }
  __syncthreads();

  for (int i = tid; i < m; i += 256)
    atomicAdd(&hist[epk[(size_t)row * CAP2 + i] >> 21], 1);  // bin = kslice>>6
  __syncthreads();

  // wave 0: find max bin b with suffix-count(b) >= K_TOP
  if (tid < 64) {
    int h[8]; int lsum = 0;
    #pragma unroll
    for (int j = 0; j < 8; ++j) { h[j] = hist[tid * 8 + j]; lsum += h[j]; }
    int cum = lsum;
    #pragma unroll
    for (int off = 1; off < 64; off <<= 1) {
      int t = __shfl_down(cum, off, 64);
      if (tid + off < 64) cum += t;
    }
    int after = __shfl_down(cum, 1, 64);
    if (tid == 63) after = 0;
    if (after < K_TOP && cum >= K_TOP) {   // crossing lane (unique)
      int run = after, bb = -1;
      #pragma unroll
      for (int j = 7; j >= 0; --j) {
        run += h[j];
        if (run >= K_TOP && bb < 0) bb = j;
      }
      s_bb = tid * 8 + bb;
    }
  }
  __syncthreads();

  bool fail = (cnt > CAP2) || (cnt < K_TOP) || (s_bb < 0);
  unsigned ks_thr = 0;
  if (!fail) {
    // reconstruct bin lower edge: key bits 31:25 == 0x60 for v in [2,32)
    float v_lo  = k2f(0xC0000000u | ((unsigned)s_bb << 16));
    float v_thr = v_lo - MARGIN;
    if (v_thr <= THR_EMIT) fail = true;
    else ks_thr = (f2k(v_thr) >> 10) & 0x7FFFu;
  }

  if (!fail) {
    for (int i = tid; i < m; i += 256) {
      unsigned p = epk[(size_t)row * CAP2 + i];
      if ((p >> 15) >= ks_thr) {
        int s = atomicAdd(&s_out, 1);
        if (s < CAND_CAP) cfeat_l[s] = (int)(p & 0x7FFFu);
      }
    }
  }
  __syncthreads();
  const int out = s_out;
  const bool fail2 = fail || (out > CAND_CAP);

  if (!fail2 && tid < out) {
    const int f = cfeat_l[tid];
    cand_idx[(size_t)row * CAND_CAP + tid] = f;
    int pp = atomicAdd(&fcnt[f], 1);
    if (pp < CAPF) fpair[(size_t)f * CAPF + pp] = (row << 8) | tid;
    else slow[row] = 1;
  }
  if (tid == 0) {
    efail[row] = fail2 ? 1 : 0;
    cand_cnt[row] = fail2 ? 0 : out;
  }
}

// ---------------------------------------------------------------------------
// Kernel 2 (old path): per-row fp32 top-k boundary + candidates; zero row.
// ---------------------------------------------------------------------------
#define TK_CAP 6144

__device__ __forceinline__ int block_reduce_sum_256(int v, volatile int* wsum, int tid) {
  #pragma unroll
  for (int off = 32; off > 0; off >>= 1) v += __shfl_down(v, off, 64);
  __syncthreads();
  if ((tid & 63) == 0) wsum[tid >> 6] = v;
  __syncthreads();
  return wsum[0] + wsum[1] + wsum[2] + wsum[3];
}

__global__ __launch_bounds__(256) void topk_kernel(
    float* __restrict__ acts, int* __restrict__ cand_idx, int* __restrict__ cand_cnt)
{
  const int row = blockIdx.x;
  const int tid = threadIdx.x;
  float* rp = acts + (size_t)row * DICT;

  __shared__ unsigned ckey[TK_CAP];
  __shared__ int      cidx[TK_CAP];
  __shared__ int      wsum[4];
  __shared__ int      s_cnt, s_out;

  float4 v[24];
  #pragma unroll
  for (int c = 0; c < 24; ++c) v[c] = *((const float4*)rp + tid + 256*c);

  int c0=0, c1=0, c2=0;
  #pragma unroll
  for (int c = 0; c < 24; ++c) {
    float e[4] = {v[c].x, v[c].y, v[c].z, v[c].w};
    #pragma unroll
    for (int j = 0; j < 4; ++j) {
      c0 += (e[j] > 2.2f) ? 1 : 0;
      c1 += (e[j] > 1.5f) ? 1 : 0;
      c2 += (e[j] > 0.5f) ? 1 : 0;
    }
  }
  int t0 = block_reduce_sum_256(c0, wsum, tid);
  int t1 = block_reduce_sum_256(c1, wsum, tid);
  int t2 = block_reduce_sum_256(c2, wsum, tid);
  float thr;
  if      (t0 >= K_TOP + 40 && t0 <= TK_CAP) thr = 2.2f;
  else if (t1 >= K_TOP + 40 && t1 <= TK_CAP) thr = 1.5f;
  else if (t2 >= K_TOP + 40 && t2 <= TK_CAP) thr = 0.5f;
  else                                       thr = -4.0f;

  if (tid == 0) { s_cnt = 0; s_out = 0; }
  __syncthreads();

  #pragma unroll
  for (int c = 0; c < 24; ++c) {
    float e[4] = {v[c].x, v[c].y, v[c].z, v[c].w};
    int base = (tid + 256*c) * 4;
    #pragma unroll
    for (int j = 0; j < 4; ++j) {
      if (e[j] > thr) {
        int s = atomicAdd(&s_cnt, 1);
        if (s < TK_CAP) { ckey[s] = f2k(e[j]); cidx[s] = base + j; }
      }
    }
  }
  __syncthreads();
  const int m = (s_cnt < TK_CAP) ? s_cnt : TK_CAP;

  unsigned prefix = 0;
  int r = K_TOP;
  for (int b = 31; b >= 0; --b) {
    unsigned bit = 1u << b;
    int c = 0;
    for (int i = tid; i < m; i += 256) {
      unsigned k = ckey[i];
      bool ok = (b == 31) ? true : ((k >> (b+1)) == (prefix >> (b+1)));
      if (ok && (k & bit)) ++c;
    }
    c = block_reduce_sum_256(c, wsum, tid);
    if (c >= r) prefix |= bit; else r -= c;
  }

  float4 z = {0.f, 0.f, 0.f, 0.f};
  #pragma unroll
  for (int c = 0; c < 24; ++c) *((float4*)rp + tid + 256*c) = z;

  const unsigned mkey = f2k(k2f(prefix) - MARGIN);
  __syncthreads();
  for (int i = tid; i < m; i += 256) {
    if (ckey[i] >= mkey) {
      int s = atomicAdd(&s_out, 1);
      if (s < CAND_CAP) cand_idx[(size_t)row * CAND_CAP + s] = cidx[i];
    }
  }
  __syncthreads();
  if (tid == 0) cand_cnt[row] = (s_out < CAND_CAP) ? s_out : CAND_CAP;
}

// ---------------------------------------------------------------------------
// Kernel F: fallback for flagged rows (expected: never). Also buckets its
// candidate entries so rerank_feat covers them.
// ---------------------------------------------------------------------------
__global__ __launch_bounds__(256) void fallback_kernel(
    const float* __restrict__ x, const float* __restrict__ W,
    const float* __restrict__ bias, const int* __restrict__ efail,
    int* __restrict__ cand_idx, int* __restrict__ cand_cnt,
    int* __restrict__ fcnt, int* __restrict__ fpair, int* __restrict__ slow)
{
  const int row = blockIdx.x;
  if (!efail[row]) return;
  const int tid = threadIdx.x;

  __shared__ float xs[D_MOD];
  __shared__ int wsum[4];
  __shared__ int s_out;

  for (int i = tid; i < D_MOD; i += 256)
    xs[i] = x[(size_t)row * D_MOD + i];
  if (tid == 0) s_out = 0;
  __syncthreads();

  unsigned kk[DICT / 256];
  for (int k = 0; k < DICT / 256; ++k) {
    const int f = tid + 256 * k;
    const float* wr = W + (size_t)f * D_MOD;
    float s = 0.f;
    for (int d = 0; d < D_MOD; d += 4) {
      float4 wv = *(const float4*)(wr + d);
      s += wv.x * xs[d] + wv.y * xs[d+1] + wv.z * xs[d+2] + wv.w * xs[d+3];
    }
    kk[k] = f2k(s + bias[f]);
  }

  unsigned prefix = 0;
  int r = K_TOP;
  for (int b = 31; b >= 0; --b) {
    unsigned bit = 1u << b;
    int c = 0;
    for (int k = 0; k < DICT / 256; ++k) {
      unsigned kv = kk[k];
      bool ok = (b == 31) ? true : ((kv >> (b+1)) == (prefix >> (b+1)));
      if (ok && (kv & bit)) ++c;
    }
    c = block_reduce_sum_256(c, wsum, tid);
    if (c >= r) prefix |= bit; else r -= c;
  }

  const unsigned mkey = f2k(k2f(prefix) - MARGIN);
  __syncthreads();
  for (int k = 0; k < DICT / 256; ++k) {
    if (kk[k] >= mkey) {
      int s = atomicAdd(&s_out, 1);
      if (s < CAND_CAP) cand_idx[(size_t)row * CAND_CAP + s] = tid + 256 * k;
    }
  }
  __syncthreads();
  const int cnt2 = (s_out < CAND_CAP) ? s_out : CAND_CAP;
  if (tid == 0) cand_cnt[row] = cnt2;
  // bucket this row's entries for rerank_feat
  if (tid < cnt2) {
    const int f = cand_idx[(size_t)row * CAND_CAP + tid];
    int pp = atomicAdd(&fcnt[f], 1);
    if (pp < CAPF) fpair[(size_t)f * CAPF + pp] = (row << 8) | tid;
    else slow[row] = 1;
  }
}

// ---------------------------------------------------------------------------
// Kernel R: feature-major fp64 rerank. Wave w of block handles feature
// f = bid*4 + w; loads W row once, streams the rows that selected it.
// Summation structure identical to the per-row rerank (numerics unchanged).
// ---------------------------------------------------------------------------
__global__ __launch_bounds__(256) void rerank_feat(
    const float* __restrict__ x, const float* __restrict__ W,
    const float* __restrict__ bias,
    const int* __restrict__ fcnt, const int* __restrict__ fpair,
    double* __restrict__ cval_g)
{
  const int lane = threadIdx.x & 63;
  const int w    = threadIdx.x >> 6;
  const int f    = blockIdx.x * 4 + w;
  int n = fcnt[f];
  if (n == 0) return;
  if (n > CAPF) n = CAPF;

  const float4* wp = (const float4*)(W + (size_t)f * D_MOD);
  const float4 w0 = wp[lane], w1 = wp[64 + lane], w2 = wp[128 + lane];
  const double bv = (double)bias[f];

  for (int e = 0; e < n; ++e) {
    const int pr  = fpair[(size_t)f * CAPF + e];
    const int row = pr >> 8, c = pr & 255;
    const float4* xp = (const float4*)(x + (size_t)row * D_MOD);
    const float4 x0 = xp[lane], x1 = xp[64 + lane], x2 = xp[128 + lane];
    double s = 0.0;
    s = fma((double)w0.x, (double)x0.x, s);
    s = fma((double)w0.y, (double)x0.y, s);
    s = fma((double)w0.z, (double)x0.z, s);
    s = fma((double)w0.w, (double)x0.w, s);
    s = fma((double)w1.x, (double)x1.x, s);
    s = fma((double)w1.y, (double)x1.y, s);
    s = fma((double)w1.z, (double)x1.z, s);
    s = fma((double)w1.w, (double)x1.w, s);
    s = fma((double)w2.x, (double)x2.x, s);
    s = fma((double)w2.y, (double)x2.y, s);
    s = fma((double)w2.z, (double)x2.z, s);
    s = fma((double)w2.w, (double)x2.w, s);
    #pragma unroll
    for (int off = 32; off > 0; off >>= 1) s += __shfl_down(s, off, 64);
    if (lane == 0) cval_g[(size_t)row * CAND_CAP + c] = s + bv;
  }
}

// ---------------------------------------------------------------------------
// Kernel 3+5 fused: per row -> load cval (or gather-rerank if slow/legacy),
// rank, scatter winners (acts pre-zeroed in prep), decode -> recon.
// ---------------------------------------------------------------------------
__global__ __launch_bounds__(256) void finalize_kernel(
    const float* __restrict__ x, const float* __restrict__ W,
    const float* __restrict__ bias,
    const int* __restrict__ cand_idx, const int* __restrict__ cand_cnt,
    const double* __restrict__ cval_g, const int* __restrict__ slow,
    const float* __restrict__ WdT, const float* __restrict__ Wd,
    float* __restrict__ acts, float* __restrict__ recon,
    int useT, int useFeat)
{
  const int row  = blockIdx.x;
  const int tid  = threadIdx.x;
  const int lane = tid & 63;
  const int wv   = tid >> 6;

  __shared__ float  xs[D_MOD];        // 3 KB
  __shared__ double cval[CAND_CAP];   // 2 KB
  __shared__ int    cidx_s[CAND_CAP]; // 1 KB
  __shared__ float  sval[K_TOP];
  __shared__ int    sidx[K_TOP];
  __shared__ float  part[4][D_MOD];   // 12 KB

  const int cnt = cand_cnt[row];
  const bool fast = useFeat && !slow[row];

  if (tid < CAND_CAP)
    cidx_s[tid] = (tid < cnt) ? cand_idx[(size_t)row * CAND_CAP + tid] : 0x7fffffff;
  if (tid < K_TOP) { sval[tid] = 0.f; sidx[tid] = 0; }

  if (fast) {
    if (tid < cnt) cval[tid] = cval_g[(size_t)row * CAND_CAP + tid];
    __syncthreads();
  } else {
    // legacy/slow path: per-row gather rerank (proven code)
    if (tid < D_MOD / 4)
      ((float4*)xs)[tid] = ((const float4*)(x + (size_t)row * D_MOD))[tid];
    __syncthreads();
    const float4* xp = (const float4*)xs;
    for (int c = wv; c < cnt; c += 4) {
      const int f = cidx_s[c];
      const float4* wp = (const float4*)(W + (size_t)f * D_MOD);
      double s = 0.0;
      #pragma unroll
      for (int j = 0; j < 3; ++j) {
        float4 wv4 = wp[j * 64 + lane];
        float4 xv4 = xp[j * 64 + lane];
        s = fma((double)wv4.x, (double)xv4.x, s);
        s = fma((double)wv4.y, (double)xv4.y, s);
        s = fma((double)wv4.z, (double)xv4.z, s);
        s = fma((double)wv4.w, (double)xv4.w, s);
      }
      #pragma unroll
      for (int off = 32; off > 0; off >>= 1) s += __shfl_down(s, off, 64);
      if (lane == 0) cval[c] = s + (double)bias[f];
    }
    __syncthreads();
  }

  {
    const bool active = (tid < cnt);
    const double myv = active ? cval[tid] : -DBL_MAX;
    const int    myi = active ? cidx_s[tid] : 0x7fffffff;
    int rank = 0;
    for (int j = 0; j < cnt; ++j) {
      double vj = cval[j];
      rank += (vj > myv || (vj == myv && cidx_s[j] < myi)) ? 1 : 0;
    }
    if (active && rank < K_TOP) {
      float a = fmaxf((float)myv, 0.f);
      sval[rank] = a;
      sidx[rank] = myi;
      acts[(size_t)row * DICT + myi] = a;   // row pre-zeroed in prep
    }
  }
  __syncthreads();

  // ---- decode phase ----
  if (useT) {
    const int w = tid >> 6, l = tid & 63;
    float4 a0 = {0.f,0.f,0.f,0.f}, a1 = a0, a2 = a0;
    #pragma unroll 4
    for (int j = 0; j < 16; ++j) {
      const float s = sval[w * 16 + j];
      const float4* wp = (const float4*)(WdT + (size_t)sidx[w * 16 + j] * D_MOD);
      float4 v0 = wp[l], v1 = wp[64 + l], v2 = wp[128 + l];
      a0.x += s * v0.x; a0.y += s * v0.y; a0.z += s * v0.z; a0.w += s * v0.w;
      a1.x += s * v1.x; a1.y += s * v1.y; a1.z += s * v1.z; a1.w += s * v1.w;
      a2.x += s * v2.x; a2.y += s * v2.y; a2.z += s * v2.z; a2.w += s * v2.w;
    }
    float4* pp = (float4*)&part[w][0];
    pp[l] = a0; pp[64 + l] = a1; pp[128 + l] = a2;
    __syncthreads();
    float* rp = recon + (size_t)row * D_MOD;
    #pragma unroll
    for (int c = 0; c < 3; ++c) {
      int d = tid + 256 * c;
      rp[d] = part[0][d] + part[1][d] + part[2][d] + part[3][d];
    }
  } else {
    float a0 = 0.f, a1 = 0.f, a2 = 0.f;
    #pragma unroll 8
    for (int j = 0; j < K_TOP; ++j) {
      float s = sval[j]; int f = sidx[j];
      a0 += s * Wd[(size_t)(tid      ) * DICT + f];
      a1 += s * Wd[(size_t)(tid + 256) * DICT + f];
      a2 += s * Wd[(size_t)(tid + 512) * DICT + f];
    }
    float* rp = recon + (size_t)row * D_MOD;
    rp[tid] = a0; rp[tid + 256] = a1; rp[tid + 512] = a2;
  }
}

// ---------------------------------------------------------------------------
// Kernel 4 (old-path only): W_dec [D_MOD, DICT] -> W_decT [DICT, D_MOD]
// ---------------------------------------------------------------------------
__global__ __launch_bounds__(256) void transpose_wdec(
    const float* __restrict__ Wd, float* __restrict__ WdT)
{
  __shared__ float tile[32][33];
  const int tid = threadIdx.x;
  const int tx = tid & 31, ty = tid >> 5;
  const int gx = blockIdx.x * 32 + tx;
  const int y0 = blockIdx.y * 32;
  #pragma unroll
  for (int i = 0; i < 32; i += 8)
    tile[ty + i][tx] = Wd[(size_t)(y0 + ty + i) * DICT + gx];
  __syncthreads();
  const int xo = y0 + tx;
  const int yo = blockIdx.x * 32;
  #pragma unroll
  for (int i = 0; i < 32; i += 8)
    WdT[(size_t)(yo + ty + i) * D_MOD + xo] = tile[tx][ty + i];
}

// ---------------------------------------------------------------------------
// Kernel Z (old path): zero acts rows (topk used to do this; keep for legacy)
// ---------------------------------------------------------------------------
__global__ __launch_bounds__(256) void zero_rows(float* __restrict__ acts)
{
  const int row = blockIdx.x;
  float4 z = {0.f, 0.f, 0.f, 0.f};
  float4* zp = (float4*)(acts + (size_t)row * DICT);
  #pragma unroll
  for (int c = 0; c < DICT / 4 / 256; ++c) zp[threadIdx.x + 256 * c] = z;
}

// ---------------------------------------------------------------------------
extern "C" void kernel_launch(void* const* d_in, const int* in_sizes, int n_in,
                              void* d_out, int out_size, void* d_ws, size_t ws_size,
                              hipStream_t stream) {
  const float* x     = (const float*)d_in[0];
  const float* W_enc = (const float*)d_in[1];
  const float* b_enc = (const float*)d_in[2];
  const float* W_dec = (const float*)d_in[3];

  float* recon = (float*)d_out;
  float* acts  = recon + (size_t)B_SZ * D_MOD;

  float*    tk_val   = (float*)d_ws;                       // (layout kept; unused)
  int*      tk_idx   = (int*)(tk_val + (size_t)B_SZ * K_TOP);
  int*      cand_cnt = (int*)(tk_idx + (size_t)B_SZ * K_TOP);
  int*      cand_idx = cand_cnt + B_SZ;
  float*    WdT      = (float*)(cand_idx + (size_t)B_SZ * CAND_CAP);
  short*    Ah       = (short*)(WdT + (size_t)DICT * D_MOD);
  short*    Wh       = Ah + (size_t)B_SZ * D_MOD;
  unsigned* epk      = (unsigned*)(Wh + (size_t)DICT * D_MOD);
  int*      ecnt     = (int*)(epk + (size_t)B_SZ * CAP2);
  int*      efail    = ecnt + B_SZ;
  int*      fcnt     = efail + B_SZ;
  int*      slow     = fcnt + DICT;
  double*   cval_g   = (double*)(slow + B_SZ);             // 8B-aligned by layout
  int*      fpair    = (int*)(cval_g + (size_t)B_SZ * CAND_CAP);

  size_t base     = (size_t)B_SZ * K_TOP * 8 + (size_t)B_SZ * 4 + (size_t)B_SZ * CAND_CAP * 4;
  size_t need_T   = base + (size_t)DICT * D_MOD * 4;
  size_t need_mf  = need_T + ((size_t)B_SZ + DICT) * D_MOD * 2;
  size_t need_new = need_mf + (size_t)B_SZ * CAP2 * 4
                  + (size_t)(3 * B_SZ + DICT) * 4
                  + (size_t)B_SZ * CAND_CAP * 8
                  + (size_t)DICT * CAPF * 4;
  int useT   = (ws_size >= need_T) ? 1 : 0;
  int useMF  = (ws_size >= need_mf) ? 1 : 0;
  int useNew = (ws_size >= need_new) ? 1 : 0;

  if (useNew) {
    // fused prep: converts + transpose + acts zero + meta zero, one launch
    hipLaunchKernelGGL(prep_kernel, dim3(NB_PREP), dim3(256), 0, stream,
                       x, W_enc, W_dec, Ah, Wh, WdT, acts, ecnt);
    hipLaunchKernelGGL(enc_gemm_emit, dim3(DICT/128, B_SZ/128), dim3(256), 0, stream,
                       Ah, Wh, b_enc, epk, ecnt);
    hipLaunchKernelGGL(select_kernel, dim3(B_SZ), dim3(256), 0, stream,
                       epk, ecnt, cand_idx, cand_cnt, efail, fcnt, fpair, slow);
    hipLaunchKernelGGL(fallback_kernel, dim3(B_SZ), dim3(256), 0, stream,
                       x, W_enc, b_enc, efail, cand_idx, cand_cnt, fcnt, fpair, slow);
    hipLaunchKernelGGL(rerank_feat, dim3(DICT/4), dim3(256), 0, stream,
                       x, W_enc, b_enc, fcnt, fpair, cval_g);
    hipLaunchKernelGGL(finalize_kernel, dim3(B_SZ), dim3(256), 0, stream,
                       x, W_enc, b_enc, cand_idx, cand_cnt, cval_g, slow,
                       WdT, W_dec, acts, recon, 1, 1);
    return;
  }

  if (useT)
    hipLaunchKernelGGL(transpose_wdec, dim3(DICT/32, D_MOD/32), dim3(256), 0, stream,
                       W_dec, WdT);

  if (useMF) {
    hipLaunchKernelGGL(cvt_half, dim3((B_SZ*D_MOD/8 + 255)/256), dim3(256), 0, stream,
                       x, Ah, B_SZ*D_MOD/8);
    hipLaunchKernelGGL(cvt_half, dim3((DICT*D_MOD/8 + 255)/256), dim3(256), 0, stream,
                       W_enc, Wh, DICT*D_MOD/8);
    hipLaunchKernelGGL(enc_gemm_mfma, dim3(DICT/128, B_SZ/128), dim3(256), 0, stream,
                       Ah, Wh, b_enc, acts);
    hipLaunchKernelGGL(topk_kernel, dim3(B_SZ), dim3(256), 0, stream,
                       acts, cand_idx, cand_cnt);
  } else {
    hipLaunchKernelGGL(enc_gemm, dim3(DICT/BN, B_SZ/BM), dim3(256), 0, stream,
                       x, W_enc, b_enc, acts);
    hipLaunchKernelGGL(topk_kernel, dim3(B_SZ), dim3(256), 0, stream,
                       acts, cand_idx, cand_cnt);
  }

  hipLaunchKernelGGL(finalize_kernel, dim3(B_SZ), dim3(256), 0, stream,
                     x, W_enc, b_enc, cand_idx, cand_cnt, cval_g, slow,
                     WdT, W_dec, acts, recon, useT, 0);
}

// Round 7
// 941.795 us; speedup vs baseline: 1.0756x; 1.0756x over previous
//
#include <hip/hip_runtime.h>
#include <cfloat>

#define B_SZ    4096
#define D_MOD   768
#define DICT    24576
#define K_TOP   64
#define CAND_CAP 256
#define MARGIN  0.04f   // legacy-path margin
#define THR_EMIT 2.0f   // emission floor; per-row 64th value is ~2.45+ min over rows
#define CAP2    1024    // per-row emission capacity (expected ~560)
#define CAP_BLK 16      // per-row per-block LDS emission capacity (lambda~2.9)
#define DELTA   0.012f  // 4x max fp16-GEMM error (~3e-3): outside band, approx rank is exact
#define BAND_CAP 32     // band members needing fp64 (expected ~1/row)

typedef __attribute__((ext_vector_type(8))) short short8;
typedef __attribute__((ext_vector_type(8))) _Float16 half8;
typedef __attribute__((ext_vector_type(4))) float floatx4;

// ---------------------------------------------------------------------------
// helpers
// ---------------------------------------------------------------------------
__device__ __forceinline__ unsigned f2k(float f) {
  unsigned u = __float_as_uint(f);
  return (u & 0x80000000u) ? ~u : (u | 0x80000000u);
}
__device__ __forceinline__ float k2f(unsigned k) {
  unsigned u = (k & 0x80000000u) ? (k & 0x7FFFFFFFu) : ~k;
  return __uint_as_float(u);
}
__device__ __forceinline__ void gload_lds16(const void* g, void* l) {
  __builtin_amdgcn_global_load_lds(
      (const __attribute__((address_space(1))) unsigned*)g,
      (__attribute__((address_space(3))) unsigned*)l, 16, 0, 0);
}
__device__ __forceinline__ void cvt8(const float* __restrict__ S,
                                     short* __restrict__ D, int idx) {
  const float4* sp = (const float4*)S + (size_t)idx * 2;
  float4 a = sp[0], b = sp[1];
  half8 h;
  h[0] = (_Float16)a.x; h[1] = (_Float16)a.y;
  h[2] = (_Float16)a.z; h[3] = (_Float16)a.w;
  h[4] = (_Float16)b.x; h[5] = (_Float16)b.y;
  h[6] = (_Float16)b.z; h[7] = (_Float16)b.w;
  *((half8*)D + idx) = h;
}

__device__ __forceinline__ int block_reduce_sum_256(int v, volatile int* wsum, int tid) {
  #pragma unroll
  for (int off = 32; off > 0; off >>= 1) v += __shfl_down(v, off, 64);
  __syncthreads();
  if ((tid & 63) == 0) wsum[tid >> 6] = v;
  __syncthreads();
  return wsum[0] + wsum[1] + wsum[2] + wsum[3];
}

// ---------------------------------------------------------------------------
// Kernel P: fused prep. Block roles:
//   [0, NB_CVT)            : fp32->fp16 convert of x then W_enc
//   [NB_CVT, +NB_TR)       : W_dec 32x32 tile transpose -> WdT
//   [NB_CVT+NB_TR, +B_SZ)  : zero one acts row each (402 MB streaming)
//   [.., +NB_META)         : zero ecnt/efail
// ---------------------------------------------------------------------------
#define N8_X    (B_SZ * D_MOD / 8)
#define N8_ALL  ((B_SZ + DICT) * D_MOD / 8)
#define NB_CVT  (N8_ALL / 256)                 // 10752
#define NB_TR   ((DICT / 32) * (D_MOD / 32))   // 18432
#define NB_META 8
#define N_META  (2 * B_SZ)                     // ecnt | efail contiguous
#define NB_PREP (NB_CVT + NB_TR + B_SZ + NB_META)

__global__ __launch_bounds__(256) void prep_kernel(
    const float* __restrict__ x, const float* __restrict__ W_enc,
    const float* __restrict__ Wd,
    short* __restrict__ Ah, short* __restrict__ Wh,
    float* __restrict__ WdT, float* __restrict__ acts,
    int* __restrict__ meta)
{
  __shared__ float tile[32][33];
  const int bid = blockIdx.x;
  const int tid = threadIdx.x;

  if (bid < NB_CVT) {
    int item = bid * 256 + tid;
    if (item < N8_X) cvt8(x, Ah, item);
    else             cvt8(W_enc, Wh, item - N8_X);
    return;
  }
  if (bid < NB_CVT + NB_TR) {
    const int t  = bid - NB_CVT;
    const int bx = t % (DICT / 32);
    const int by = t / (DICT / 32);
    const int tx = tid & 31, ty = tid >> 5;   // 32 x 8
    const int gx = bx * 32 + tx;
    const int y0 = by * 32;
    #pragma unroll
    for (int i = 0; i < 32; i += 8)
      tile[ty + i][tx] = Wd[(size_t)(y0 + ty + i) * DICT + gx];
    __syncthreads();
    const int xo = y0 + tx;
    const int yo = bx * 32;
    #pragma unroll
    for (int i = 0; i < 32; i += 8)
      WdT[(size_t)(yo + ty + i) * D_MOD + xo] = tile[tx][ty + i];
    return;
  }
  if (bid < NB_CVT + NB_TR + B_SZ) {
    const int row = bid - (NB_CVT + NB_TR);
    float4 z = {0.f, 0.f, 0.f, 0.f};
    float4* zp = (float4*)(acts + (size_t)row * DICT);
    #pragma unroll
    for (int c = 0; c < DICT / 4 / 256; ++c) zp[tid + 256 * c] = z;
    return;
  }
  const int b = bid - (NB_CVT + NB_TR + B_SZ);
  for (int i = b * 256 + tid; i < N_META; i += NB_META * 256) meta[i] = 0;
}

// ---------------------------------------------------------------------------
// Kernel 0 (old-path only): fp32 -> fp16 convert
// ---------------------------------------------------------------------------
__global__ __launch_bounds__(256) void cvt_half(
    const float* __restrict__ S, short* __restrict__ D, int n8)
{
  int idx = blockIdx.x * 256 + threadIdx.x;
  if (idx >= n8) return;
  cvt8(S, D, idx);
}

// ---------------------------------------------------------------------------
// Kernel 1a: MFMA encoder GEMM (double-buffered) + LDS-aggregated emission.
// Emits FULL fp32 value: (f2k(v), idx) uint2 per candidate (v > THR_EMIT).
// ---------------------------------------------------------------------------
#define LOFF (128 * 32)   // shorts per LDS buffer

__global__ __launch_bounds__(256) void enc_gemm_emit(
    const short* __restrict__ Ah,   // [B_SZ, D_MOD] fp16 bits
    const short* __restrict__ Wh,   // [DICT, D_MOD] fp16 bits
    const float* __restrict__ bias,
    uint2* __restrict__ epk,        // [B_SZ, CAP2]
    int* __restrict__ ecnt)         // [B_SZ]
{
  __shared__ __align__(16) short As[2][128][32];
  __shared__ __align__(16) short Bs[2][128][32];

  const int tid = threadIdx.x;
  const int l   = tid & 63;
  const int w   = tid >> 6;
  const int n0  = blockIdx.x * 128;
  const int m0  = blockIdx.y * 128;
  const int wr  = w >> 1, wc = w & 1;

  const int srow = (w * 2) * 16 + (l >> 2);
  const int kc   = (l & 3) * 8;
  const short* gA0 = Ah + (size_t)(m0 + srow) * D_MOD + kc;
  const short* gA1 = gA0 + (size_t)16 * D_MOD;
  const short* gB0 = Wh + (size_t)(n0 + srow) * D_MOD + kc;
  const short* gB1 = gB0 + (size_t)16 * D_MOD;
  short* lA0 = &As[0][(w * 2) * 16][0];
  short* lA1 = lA0 + 16 * 32;
  short* lB0 = &Bs[0][(w * 2) * 16][0];
  short* lB1 = lB0 + 16 * 32;

#define STAGE(buf, kt) do {                      \
    gload_lds16(gA0 + (kt), lA0 + (buf) * LOFF); \
    gload_lds16(gA1 + (kt), lA1 + (buf) * LOFF); \
    gload_lds16(gB0 + (kt), lB0 + (buf) * LOFF); \
    gload_lds16(gB1 + (kt), lB1 + (buf) * LOFF); \
  } while (0)

  floatx4 acc[4][4];
  #pragma unroll
  for (int i = 0; i < 4; ++i)
    #pragma unroll
    for (int j = 0; j < 4; ++j) acc[i][j] = (floatx4){0.f, 0.f, 0.f, 0.f};

  const int fr = l & 15;
  const int fq = (l >> 4) * 8;

  STAGE(0, 0);
  __syncthreads();
  int cur = 0;

  for (int kt = 32; kt <= D_MOD; kt += 32) {
    if (kt < D_MOD) STAGE(cur ^ 1, kt);
    half8 af[4], bf[4];
    #pragma unroll
    for (int t = 0; t < 4; ++t) {
      af[t] = *(const half8*)&As[cur][wr * 64 + t * 16 + fr][fq];
      bf[t] = *(const half8*)&Bs[cur][wc * 64 + t * 16 + fr][fq];
    }
    #pragma unroll
    for (int i = 0; i < 4; ++i)
      #pragma unroll
      for (int j = 0; j < 4; ++j)
        acc[i][j] = __builtin_amdgcn_mfma_f32_16x16x32_f16(af[i], bf[j], acc[i][j], 0, 0, 0);
    __syncthreads();
    cur ^= 1;
  }
#undef STAGE

  // ---- epilogue: LDS-aggregated emission (uint2 = key,idx) ----
  uint2* elist  = (uint2*)&As[0][0][0];   // [128][CAP_BLK] uint2 = 16 KB = all of As
  int*   ecnt_s = (int*)&Bs[0][0][0];     // [128]
  if (tid < 128) ecnt_s[tid] = 0;
  __syncthreads();

  const int rq = (l >> 4) * 4;
  #pragma unroll
  for (int j = 0; j < 4; ++j) {
    const int n = n0 + wc * 64 + j * 16 + fr;
    const float bv = bias[n];
    #pragma unroll
    for (int i = 0; i < 4; ++i) {
      const int lr0 = wr * 64 + i * 16 + rq;
      #pragma unroll
      for (int r = 0; r < 4; ++r) {
        float v = acc[i][j][r] + bv;
        if (v > THR_EMIT) {
          const int lr = lr0 + r;
          int s = atomicAdd(&ecnt_s[lr], 1);
          if (s < CAP_BLK) elist[lr * CAP_BLK + s] = make_uint2(f2k(v), (unsigned)n);
          else atomicAdd(&ecnt[m0 + lr], CAP2 + 1);  // poison -> rowfinal fails -> fallback
        }
      }
    }
  }
  __syncthreads();

  if (tid < 128) {
    int c = ecnt_s[tid];
    if (c > 0) {
      if (c > CAP_BLK) c = CAP_BLK;
      const int row = m0 + tid;
      int base = atomicAdd(&ecnt[row], c);
      for (int s = 0; s < c; ++s) {
        int p = base + s;
        if (p < CAP2) epk[(size_t)row * CAP2 + p] = elist[tid * CAP_BLK + s];
      }
    }
  }
}

// ---------------------------------------------------------------------------
// Kernel R: per-row final. Radix top-64 boundary over emitted fp32 keys;
// sure-ins (key > b64+DELTA) keep approx values; band (|v-b64|<=DELTA) gets
// exact fp64 dot + rank; scatter acts; sparse decode -> recon.
// Any violated invariant -> efail (fallback + finalize2 cover the row).
// ---------------------------------------------------------------------------
__global__ __launch_bounds__(256) void rowfinal_kernel(
    const uint2* __restrict__ epk, const int* __restrict__ ecnt,
    const float* __restrict__ x, const float* __restrict__ W,
    const float* __restrict__ bias, const float* __restrict__ WdT,
    float* __restrict__ acts, float* __restrict__ recon,
    int* __restrict__ efail)
{
  const int row  = blockIdx.x;
  const int tid  = threadIdx.x;
  const int lane = tid & 63;
  const int wv   = tid >> 6;

  __shared__ unsigned       ckey[CAP2];      // 4 KB
  __shared__ unsigned short cidx[CAP2];      // 2 KB
  __shared__ float  xs[D_MOD];               // 3 KB
  __shared__ float  part[4][D_MOD];          // 12 KB
  __shared__ double bval[BAND_CAP];
  __shared__ int    bslot[BAND_CAP];
  __shared__ float  sval[K_TOP];
  __shared__ int    sidx[K_TOP];
  __shared__ int    wsum[4];
  __shared__ int    s_nin, s_bn;

  const int cnt = ecnt[row];
  bool fail = (cnt < K_TOP) || (cnt > CAP2);
  const int m = fail ? 0 : cnt;

  for (int i = tid; i < m; i += 256) {
    uint2 p = epk[(size_t)row * CAP2 + i];
    ckey[i] = p.x; cidx[i] = (unsigned short)p.y;
  }
  if (tid < D_MOD / 4)
    ((float4*)xs)[tid] = ((const float4*)(x + (size_t)row * D_MOD))[tid];
  if (tid < K_TOP) { sval[tid] = 0.f; sidx[tid] = 0; }
  if (tid == 0) { s_nin = 0; s_bn = 0; }
  __syncthreads();

  // exact radix: key of the 64th largest approx value
  unsigned prefix = 0;
  int r = K_TOP;
  for (int b = 31; b >= 0; --b) {
    unsigned bit = 1u << b;
    int c = 0;
    for (int i = tid; i < m; i += 256) {
      unsigned k = ckey[i];
      bool ok = (b == 31) ? true : ((k >> (b + 1)) == (prefix >> (b + 1)));
      if (ok && (k & bit)) ++c;
    }
    c = block_reduce_sum_256(c, wsum, tid);
    if (c >= r) prefix |= bit; else r -= c;
  }

  const float b64f = k2f(prefix);
  if (b64f - DELTA <= THR_EMIT) fail = true;   // band must be fully inside emitted set
  const unsigned kin = f2k(b64f + DELTA);
  const unsigned klo = f2k(b64f - DELTA);

  if (!fail) {
    for (int i = tid; i < m; i += 256) {
      unsigned k = ckey[i];
      if (k > kin) {                       // certainly top-64: approx value is final
        int s = atomicAdd(&s_nin, 1);
        if (s < K_TOP) { sval[s] = k2f(k); sidx[s] = cidx[i]; }
      } else if (k >= klo) {               // boundary band: needs fp64
        int e = atomicAdd(&s_bn, 1);
        if (e < BAND_CAP) bslot[e] = i;
      }
    }
  }
  __syncthreads();
  const int A  = s_nin;
  const int bn = s_bn;
  if (A >= K_TOP || bn > BAND_CAP) fail = true;
  const int need = K_TOP - A;
  if (!fail && bn < need) fail = true;     // invariant guard (cannot happen)

  if (!fail) {
    // fp64 exact dot for band members (same summation as proven rerank)
    for (int e = wv; e < bn; e += 4) {
      const int f = cidx[bslot[e]];
      const float4* wp = (const float4*)(W + (size_t)f * D_MOD);
      const float4* xp = (const float4*)xs;
      double s = 0.0;
      #pragma unroll
      for (int j = 0; j < 3; ++j) {
        float4 w4 = wp[j * 64 + lane];
        float4 x4 = xp[j * 64 + lane];
        s = fma((double)w4.x, (double)x4.x, s);
        s = fma((double)w4.y, (double)x4.y, s);
        s = fma((double)w4.z, (double)x4.z, s);
        s = fma((double)w4.w, (double)x4.w, s);
      }
      #pragma unroll
      for (int off = 32; off > 0; off >>= 1) s += __shfl_down(s, off, 64);
      if (lane == 0) bval[e] = s + (double)bias[f];
    }
    __syncthreads();

    if (tid < bn) {
      const double myv = bval[tid];
      const int    myi = cidx[bslot[tid]];
      int rank = 0;
      for (int j = 0; j < bn; ++j) {
        double vj = bval[j];
        rank += (vj > myv || (vj == myv && (int)cidx[bslot[j]] < myi)) ? 1 : 0;
      }
      if (rank < need) {
        int slot = A + rank;
        sval[slot] = fmaxf((float)myv, 0.f);
        sidx[slot] = myi;
      }
    }
    __syncthreads();

    if (tid < K_TOP)
      acts[(size_t)row * DICT + sidx[tid]] = sval[tid];   // row pre-zeroed in prep
    __syncthreads();

    // ---- decode (proven 4-wave float4 / part-reduce) ----
    float4 a0 = {0.f,0.f,0.f,0.f}, a1 = a0, a2 = a0;
    #pragma unroll 4
    for (int j = 0; j < 16; ++j) {
      const float s = sval[wv * 16 + j];
      const float4* wp = (const float4*)(WdT + (size_t)sidx[wv * 16 + j] * D_MOD);
      float4 v0 = wp[lane], v1 = wp[64 + lane], v2 = wp[128 + lane];
      a0.x += s * v0.x; a0.y += s * v0.y; a0.z += s * v0.z; a0.w += s * v0.w;
      a1.x += s * v1.x; a1.y += s * v1.y; a1.z += s * v1.z; a1.w += s * v1.w;
      a2.x += s * v2.x; a2.y += s * v2.y; a2.z += s * v2.z; a2.w += s * v2.w;
    }
    float4* pp = (float4*)&part[wv][0];
    pp[lane] = a0; pp[64 + lane] = a1; pp[128 + lane] = a2;
    __syncthreads();
    float* rp = recon + (size_t)row * D_MOD;
    #pragma unroll
    for (int c = 0; c < 3; ++c) {
      int d = tid + 256 * c;
      rp[d] = part[0][d] + part[1][d] + part[2][d] + part[3][d];
    }
  }
  if (tid == 0) efail[row] = fail ? 1 : 0;
}

// ---------------------------------------------------------------------------
// Kernel F: dense fallback for flagged rows (expected: never).
// ---------------------------------------------------------------------------
__global__ __launch_bounds__(256) void fallback_kernel(
    const float* __restrict__ x, const float* __restrict__ W,
    const float* __restrict__ bias, const int* __restrict__ efail,
    int* __restrict__ cand_idx, int* __restrict__ cand_cnt)
{
  const int row = blockIdx.x;
  if (!efail[row]) return;
  const int tid = threadIdx.x;

  __shared__ float xs[D_MOD];
  __shared__ int wsum[4];
  __shared__ int s_out;

  for (int i = tid; i < D_MOD; i += 256)
    xs[i] = x[(size_t)row * D_MOD + i];
  if (tid == 0) s_out = 0;
  __syncthreads();

  unsigned kk[DICT / 256];
  for (int k = 0; k < DICT / 256; ++k) {
    const int f = tid + 256 * k;
    const float* wr = W + (size_t)f * D_MOD;
    float s = 0.f;
    for (int d = 0; d < D_MOD; d += 4) {
      float4 wv = *(const float4*)(wr + d);
      s += wv.x * xs[d] + wv.y * xs[d+1] + wv.z * xs[d+2] + wv.w * xs[d+3];
    }
    kk[k] = f2k(s + bias[f]);
  }

  unsigned prefix = 0;
  int r = K_TOP;
  for (int b = 31; b >= 0; --b) {
    unsigned bit = 1u << b;
    int c = 0;
    for (int k = 0; k < DICT / 256; ++k) {
      unsigned kv = kk[k];
      bool ok = (b == 31) ? true : ((kv >> (b+1)) == (prefix >> (b+1)));
      if (ok && (kv & bit)) ++c;
    }
    c = block_reduce_sum_256(c, wsum, tid);
    if (c >= r) prefix |= bit; else r -= c;
  }

  const unsigned mkey = f2k(k2f(prefix) - MARGIN);
  __syncthreads();
  for (int k = 0; k < DICT / 256; ++k) {
    if (kk[k] >= mkey) {
      int s = atomicAdd(&s_out, 1);
      if (s < CAND_CAP) cand_idx[(size_t)row * CAND_CAP + s] = tid + 256 * k;
    }
  }
  __syncthreads();
  if (tid == 0) cand_cnt[row] = (s_out < CAND_CAP) ? s_out : CAND_CAP;
}

// ---------------------------------------------------------------------------
// Kernel 3+5 (legacy / efail path): per-row gather fp64 rerank + decode.
// onlyFail=1 -> process only efail rows (acts pre-zeroed in prep).
// ---------------------------------------------------------------------------
__global__ __launch_bounds__(256) void finalize2_kernel(
    const float* __restrict__ x, const float* __restrict__ W,
    const float* __restrict__ bias,
    const int* __restrict__ cand_idx, const int* __restrict__ cand_cnt,
    const int* __restrict__ efail,
    const float* __restrict__ WdT, const float* __restrict__ Wd,
    float* __restrict__ acts, float* __restrict__ recon,
    int useT, int onlyFail)
{
  const int row  = blockIdx.x;
  if (onlyFail && !efail[row]) return;
  const int tid  = threadIdx.x;
  const int lane = tid & 63;
  const int wv   = tid >> 6;

  __shared__ float  xs[D_MOD];
  __shared__ double cval[CAND_CAP];
  __shared__ int    cidx_s[CAND_CAP];
  __shared__ float  sval[K_TOP];
  __shared__ int    sidx[K_TOP];
  __shared__ float  part[4][D_MOD];

  const int cnt = cand_cnt[row];

  if (tid < D_MOD / 4)
    ((float4*)xs)[tid] = ((const float4*)(x + (size_t)row * D_MOD))[tid];
  if (tid < CAND_CAP)
    cidx_s[tid] = (tid < cnt) ? cand_idx[(size_t)row * CAND_CAP + tid] : 0x7fffffff;
  if (tid < K_TOP) { sval[tid] = 0.f; sidx[tid] = 0; }
  __syncthreads();

  const float4* xp = (const float4*)xs;
  for (int c = wv; c < cnt; c += 4) {
    const int f = cidx_s[c];
    const float4* wp = (const float4*)(W + (size_t)f * D_MOD);
    double s = 0.0;
    #pragma unroll
    for (int j = 0; j < 3; ++j) {
      float4 wv4 = wp[j * 64 + lane];
      float4 xv4 = xp[j * 64 + lane];
      s = fma((double)wv4.x, (double)xv4.x, s);
      s = fma((double)wv4.y, (double)xv4.y, s);
      s = fma((double)wv4.z, (double)xv4.z, s);
      s = fma((double)wv4.w, (double)xv4.w, s);
    }
    #pragma unroll
    for (int off = 32; off > 0; off >>= 1) s += __shfl_down(s, off, 64);
    if (lane == 0) cval[c] = s + (double)bias[f];
  }
  __syncthreads();

  {
    const bool active = (tid < cnt);
    const double myv = active ? cval[tid] : -DBL_MAX;
    const int    myi = active ? cidx_s[tid] : 0x7fffffff;
    int rank = 0;
    for (int j = 0; j < cnt; ++j) {
      double vj = cval[j];
      rank += (vj > myv || (vj == myv && cidx_s[j] < myi)) ? 1 : 0;
    }
    if (active && rank < K_TOP) {
      float a = fmaxf((float)myv, 0.f);
      sval[rank] = a;
      sidx[rank] = myi;
      acts[(size_t)row * DICT + myi] = a;
    }
  }
  __syncthreads();

  if (useT) {
    float4 a0 = {0.f,0.f,0.f,0.f}, a1 = a0, a2 = a0;
    #pragma unroll 4
    for (int j = 0; j < 16; ++j) {
      const float s = sval[wv * 16 + j];
      const float4* wp = (const float4*)(WdT + (size_t)sidx[wv * 16 + j] * D_MOD);
      float4 v0 = wp[lane], v1 = wp[64 + lane], v2 = wp[128 + lane];
      a0.x += s * v0.x; a0.y += s * v0.y; a0.z += s * v0.z; a0.w += s * v0.w;
      a1.x += s * v1.x; a1.y += s * v1.y; a1.z += s * v1.z; a1.w += s * v1.w;
      a2.x += s * v2.x; a2.y += s * v2.y; a2.z += s * v2.z; a2.w += s * v2.w;
    }
    float4* pp = (float4*)&part[wv][0];
    pp[lane] = a0; pp[64 + lane] = a1; pp[128 + lane] = a2;
    __syncthreads();
    float* rp = recon + (size_t)row * D_MOD;
    #pragma unroll
    for (int c = 0; c < 3; ++c) {
      int d = tid + 256 * c;
      rp[d] = part[0][d] + part[1][d] + part[2][d] + part[3][d];
    }
  } else {
    float a0 = 0.f, a1 = 0.f, a2 = 0.f;
    #pragma unroll 8
    for (int j = 0; j < K_TOP; ++j) {
      float s = sval[j]; int f = sidx[j];
      a0 += s * Wd[(size_t)(tid      ) * DICT + f];
      a1 += s * Wd[(size_t)(tid + 256) * DICT + f];
      a2 += s * Wd[(size_t)(tid + 512) * DICT + f];
    }
    float* rp = recon + (size_t)row * D_MOD;
    rp[tid] = a0; rp[tid + 256] = a1; rp[tid + 512] = a2;
  }
}

// ---------------------------------------------------------------------------
// Legacy kernels (small-ws paths)
// ---------------------------------------------------------------------------
__global__ __launch_bounds__(256) void enc_gemm_mfma(
    const short* __restrict__ Ah, const short* __restrict__ Wh,
    const float* __restrict__ bias, float* __restrict__ C)
{
  __shared__ short As[128][32];
  __shared__ short Bs[128][32];

  const int tid = threadIdx.x;
  const int l   = tid & 63;
  const int w   = tid >> 6;
  const int n0  = blockIdx.x * 128;
  const int m0  = blockIdx.y * 128;
  const int wr  = w >> 1, wc = w & 1;

  const int srow = (w * 2) * 16 + (l >> 2);
  const int kc   = (l & 3) * 8;
  const short* gA0 = Ah + (size_t)(m0 + srow) * D_MOD + kc;
  const short* gA1 = gA0 + (size_t)16 * D_MOD;
  const short* gB0 = Wh + (size_t)(n0 + srow) * D_MOD + kc;
  const short* gB1 = gB0 + (size_t)16 * D_MOD;
  short* lA0 = &As[(w * 2) * 16][0];
  short* lA1 = lA0 + 16 * 32;
  short* lB0 = &Bs[(w * 2) * 16][0];
  short* lB1 = lB0 + 16 * 32;

  floatx4 acc[4][4];
  #pragma unroll
  for (int i = 0; i < 4; ++i)
    #pragma unroll
    for (int j = 0; j < 4; ++j) acc[i][j] = (floatx4){0.f, 0.f, 0.f, 0.f};

  const int fr = l & 15;
  const int fq = (l >> 4) * 8;

  for (int kt = 0; kt < D_MOD; kt += 32) {
    __syncthreads();
    gload_lds16(gA0 + kt, lA0);
    gload_lds16(gA1 + kt, lA1);
    gload_lds16(gB0 + kt, lB0);
    gload_lds16(gB1 + kt, lB1);
    __syncthreads();
    half8 af[4], bf[4];
    #pragma unroll
    for (int t = 0; t < 4; ++t) {
      af[t] = *(const half8*)&As[wr * 64 + t * 16 + fr][fq];
      bf[t] = *(const half8*)&Bs[wc * 64 + t * 16 + fr][fq];
    }
    #pragma unroll
    for (int i = 0; i < 4; ++i)
      #pragma unroll
      for (int j = 0; j < 4; ++j)
        acc[i][j] = __builtin_amdgcn_mfma_f32_16x16x32_f16(af[i], bf[j], acc[i][j], 0, 0, 0);
  }

  const int rq = (l >> 4) * 4;
  #pragma unroll
  for (int j = 0; j < 4; ++j) {
    const int n = n0 + wc * 64 + j * 16 + fr;
    const float bv = bias[n];
    #pragma unroll
    for (int i = 0; i < 4; ++i) {
      const int mb = m0 + wr * 64 + i * 16 + rq;
      #pragma unroll
      for (int r = 0; r < 4; ++r)
        C[(size_t)(mb + r) * DICT + n] = acc[i][j][r] + bv;
    }
  }
}

#define BM 128
#define BN 128
#define BK 16
#define LDP (BM + 4)

__global__ __launch_bounds__(256) void enc_gemm(
    const float* __restrict__ A, const float* __restrict__ W,
    const float* __restrict__ bias, float* __restrict__ C)
{
  __shared__ float Asf[BK][LDP];
  __shared__ float Bsf[BK][LDP];

  const int tid = threadIdx.x;
  const int n0 = blockIdx.x * BN;
  const int m0 = blockIdx.y * BM;
  const int tx = tid & 15;
  const int ty = tid >> 4;
  const int lrow = tid >> 2;
  const int lc4  = tid & 3;

  const float* Aptr  = A + (size_t)(m0 + lrow) * D_MOD + lc4 * 4;
  const float* Aptr2 = Aptr + (size_t)64 * D_MOD;
  const float* Wptr  = W + (size_t)(n0 + lrow) * D_MOD + lc4 * 4;
  const float* Wptr2 = Wptr + (size_t)64 * D_MOD;

  float acc[8][8];
  #pragma unroll
  for (int i = 0; i < 8; ++i)
    #pragma unroll
    for (int j = 0; j < 8; ++j) acc[i][j] = 0.f;

  for (int kt = 0; kt < D_MOD; kt += BK) {
    float4 a0 = *(const float4*)(Aptr  + kt);
    float4 a1 = *(const float4*)(Aptr2 + kt);
    float4 b0 = *(const float4*)(Wptr  + kt);
    float4 b1 = *(const float4*)(Wptr2 + kt);
    __syncthreads();
    Asf[lc4*4+0][lrow] = a0.x;  Asf[lc4*4+1][lrow] = a0.y;
    Asf[lc4*4+2][lrow] = a0.z;  Asf[lc4*4+3][lrow] = a0.w;
    Asf[lc4*4+0][64+lrow] = a1.x;  Asf[lc4*4+1][64+lrow] = a1.y;
    Asf[lc4*4+2][64+lrow] = a1.z;  Asf[lc4*4+3][64+lrow] = a1.w;
    Bsf[lc4*4+0][lrow] = b0.x;  Bsf[lc4*4+1][lrow] = b0.y;
    Bsf[lc4*4+2][lrow] = b0.z;  Bsf[lc4*4+3][lrow] = b0.w;
    Bsf[lc4*4+0][64+lrow] = b1.x;  Bsf[lc4*4+1][64+lrow] = b1.y;
    Bsf[lc4*4+2][64+lrow] = b1.z;  Bsf[lc4*4+3][64+lrow] = b1.w;
    __syncthreads();
    #pragma unroll
    for (int k = 0; k < BK; ++k) {
      float a[8], b[8];
      *(float4*)&a[0] = *(const float4*)&Asf[k][ty*4];
      *(float4*)&a[4] = *(const float4*)&Asf[k][64 + ty*4];
      *(float4*)&b[0] = *(const float4*)&Bsf[k][tx*4];
      *(float4*)&b[4] = *(const float4*)&Bsf[k][64 + tx*4];
      #pragma unroll
      for (int i = 0; i < 8; ++i)
        #pragma unroll
        for (int j = 0; j < 8; ++j) acc[i][j] += a[i] * b[j];
    }
  }

  float4 bs0 = *(const float4*)(bias + n0 + tx*4);
  float4 bs1 = *(const float4*)(bias + n0 + 64 + tx*4);
  #pragma unroll
  for (int i = 0; i < 8; ++i) {
    int r = m0 + ((i < 4) ? (ty*4 + i) : (64 + ty*4 + i - 4));
    float* cp = C + (size_t)r * DICT + n0 + tx*4;
    float4 o0 = {acc[i][0]+bs0.x, acc[i][1]+bs0.y, acc[i][2]+bs0.z, acc[i][3]+bs0.w};
    float4 o1 = {acc[i][4]+bs1.x, acc[i][5]+bs1.y, acc[i][6]+bs1.z, acc[i][7]+bs1.w};
    *(float4*)cp = o0;
    *(float4*)(cp + 64) = o1;
  }
}

#define TK_CAP 6144

__global__ __launch_bounds__(256) void topk_kernel(
    float* __restrict__ acts, int* __restrict__ cand_idx, int* __restrict__ cand_cnt)
{
  const int row = blockIdx.x;
  const int tid = threadIdx.x;
  float* rp = acts + (size_t)row * DICT;

  __shared__ unsigned ckey[TK_CAP];
  __shared__ int      cidx[TK_CAP];
  __shared__ int      wsum[4];
  __shared__ int      s_cnt, s_out;

  float4 v[24];
  #pragma unroll
  for (int c = 0; c < 24; ++c) v[c] = *((const float4*)rp + tid + 256*c);

  int c0=0, c1=0, c2=0;
  #pragma unroll
  for (int c = 0; c < 24; ++c) {
    float e[4] = {v[c].x, v[c].y, v[c].z, v[c].w};
    #pragma unroll
    for (int j = 0; j < 4; ++j) {
      c0 += (e[j] > 2.2f) ? 1 : 0;
      c1 += (e[j] > 1.5f) ? 1 : 0;
      c2 += (e[j] > 0.5f) ? 1 : 0;
    }
  }
  int t0 = block_reduce_sum_256(c0, wsum, tid);
  int t1 = block_reduce_sum_256(c1, wsum, tid);
  int t2 = block_reduce_sum_256(c2, wsum, tid);
  float thr;
  if      (t0 >= K_TOP + 40 && t0 <= TK_CAP) thr = 2.2f;
  else if (t1 >= K_TOP + 40 && t1 <= TK_CAP) thr = 1.5f;
  else if (t2 >= K_TOP + 40 && t2 <= TK_CAP) thr = 0.5f;
  else                                       thr = -4.0f;

  if (tid == 0) { s_cnt = 0; s_out = 0; }
  __syncthreads();

  #pragma unroll
  for (int c = 0; c < 24; ++c) {
    float e[4] = {v[c].x, v[c].y, v[c].z, v[c].w};
    int base = (tid + 256*c) * 4;
    #pragma unroll
    for (int j = 0; j < 4; ++j) {
      if (e[j] > thr) {
        int s = atomicAdd(&s_cnt, 1);
        if (s < TK_CAP) { ckey[s] = f2k(e[j]); cidx[s] = base + j; }
      }
    }
  }
  __syncthreads();
  const int m = (s_cnt < TK_CAP) ? s_cnt : TK_CAP;

  unsigned prefix = 0;
  int r = K_TOP;
  for (int b = 31; b >= 0; --b) {
    unsigned bit = 1u << b;
    int c = 0;
    for (int i = tid; i < m; i += 256) {
      unsigned k = ckey[i];
      bool ok = (b == 31) ? true : ((k >> (b+1)) == (prefix >> (b+1)));
      if (ok && (k & bit)) ++c;
    }
    c = block_reduce_sum_256(c, wsum, tid);
    if (c >= r) prefix |= bit; else r -= c;
  }

  float4 z = {0.f, 0.f, 0.f, 0.f};
  #pragma unroll
  for (int c = 0; c < 24; ++c) *((float4*)rp + tid + 256*c) = z;

  const unsigned mkey = f2k(k2f(prefix) - MARGIN);
  __syncthreads();
  for (int i = tid; i < m; i += 256) {
    if (ckey[i] >= mkey) {
      int s = atomicAdd(&s_out, 1);
      if (s < CAND_CAP) cand_idx[(size_t)row * CAND_CAP + s] = cidx[i];
    }
  }
  __syncthreads();
  if (tid == 0) cand_cnt[row] = (s_out < CAND_CAP) ? s_out : CAND_CAP;
}

__global__ __launch_bounds__(256) void transpose_wdec(
    const float* __restrict__ Wd, float* __restrict__ WdT)
{
  __shared__ float tile[32][33];
  const int tid = threadIdx.x;
  const int tx = tid & 31, ty = tid >> 5;
  const int gx = blockIdx.x * 32 + tx;
  const int y0 = blockIdx.y * 32;
  #pragma unroll
  for (int i = 0; i < 32; i += 8)
    tile[ty + i][tx] = Wd[(size_t)(y0 + ty + i) * DICT + gx];
  __syncthreads();
  const int xo = y0 + tx;
  const int yo = blockIdx.x * 32;
  #pragma unroll
  for (int i = 0; i < 32; i += 8)
    WdT[(size_t)(yo + ty + i) * D_MOD + xo] = tile[tx][ty + i];
}

// ---------------------------------------------------------------------------
extern "C" void kernel_launch(void* const* d_in, const int* in_sizes, int n_in,
                              void* d_out, int out_size, void* d_ws, size_t ws_size,
                              hipStream_t stream) {
  const float* x     = (const float*)d_in[0];
  const float* W_enc = (const float*)d_in[1];
  const float* b_enc = (const float*)d_in[2];
  const float* W_dec = (const float*)d_in[3];

  float* recon = (float*)d_out;
  float* acts  = recon + (size_t)B_SZ * D_MOD;

  float*    tk_val   = (float*)d_ws;                       // (layout kept; unused)
  int*      tk_idx   = (int*)(tk_val + (size_t)B_SZ * K_TOP);
  int*      cand_cnt = (int*)(tk_idx + (size_t)B_SZ * K_TOP);
  int*      cand_idx = cand_cnt + B_SZ;
  float*    WdT      = (float*)(cand_idx + (size_t)B_SZ * CAND_CAP);
  short*    Ah       = (short*)(WdT + (size_t)DICT * D_MOD);
  short*    Wh       = Ah + (size_t)B_SZ * D_MOD;
  uint2*    epk      = (uint2*)(Wh + (size_t)DICT * D_MOD);  // 8B-aligned by layout
  int*      ecnt     = (int*)(epk + (size_t)B_SZ * CAP2);
  int*      efail    = ecnt + B_SZ;

  size_t base     = (size_t)B_SZ * K_TOP * 8 + (size_t)B_SZ * 4 + (size_t)B_SZ * CAND_CAP * 4;
  size_t need_T   = base + (size_t)DICT * D_MOD * 4;
  size_t need_mf  = need_T + ((size_t)B_SZ + DICT) * D_MOD * 2;
  size_t need_new = need_mf + (size_t)B_SZ * CAP2 * 8 + (size_t)B_SZ * 8;
  int useT   = (ws_size >= need_T) ? 1 : 0;
  int useMF  = (ws_size >= need_mf) ? 1 : 0;
  int useNew = (ws_size >= need_new) ? 1 : 0;

  if (useNew) {
    hipLaunchKernelGGL(prep_kernel, dim3(NB_PREP), dim3(256), 0, stream,
                       x, W_enc, W_dec, Ah, Wh, WdT, acts, ecnt);
    hipLaunchKernelGGL(enc_gemm_emit, dim3(DICT/128, B_SZ/128), dim3(256), 0, stream,
                       Ah, Wh, b_enc, epk, ecnt);
    hipLaunchKernelGGL(rowfinal_kernel, dim3(B_SZ), dim3(256), 0, stream,
                       epk, ecnt, x, W_enc, b_enc, WdT, acts, recon, efail);
    hipLaunchKernelGGL(fallback_kernel, dim3(B_SZ), dim3(256), 0, stream,
                       x, W_enc, b_enc, efail, cand_idx, cand_cnt);
    hipLaunchKernelGGL(finalize2_kernel, dim3(B_SZ), dim3(256), 0, stream,
                       x, W_enc, b_enc, cand_idx, cand_cnt, efail,
                       WdT, W_dec, acts, recon, 1, 1);
    return;
  }

  if (useT)
    hipLaunchKernelGGL(transpose_wdec, dim3(DICT/32, D_MOD/32), dim3(256), 0, stream,
                       W_dec, WdT);

  if (useMF) {
    hipLaunchKernelGGL(cvt_half, dim3((B_SZ*D_MOD/8 + 255)/256), dim3(256), 0, stream,
                       x, Ah, B_SZ*D_MOD/8);
    hipLaunchKernelGGL(cvt_half, dim3((DICT*D_MOD/8 + 255)/256), dim3(256), 0, stream,
                       W_enc, Wh, DICT*D_MOD/8);
    hipLaunchKernelGGL(enc_gemm_mfma, dim3(DICT/128, B_SZ/128), dim3(256), 0, stream,
                       Ah, Wh, b_enc, acts);
    hipLaunchKernelGGL(topk_kernel, dim3(B_SZ), dim3(256), 0, stream,
                       acts, cand_idx, cand_cnt);
  } else {
    hipLaunchKernelGGL(enc_gemm, dim3(DICT/BN, B_SZ/BM), dim3(256), 0, stream,
                       x, W_enc, b_enc, acts);
    hipLaunchKernelGGL(topk_kernel, dim3(B_SZ), dim3(256), 0, stream,
                       acts, cand_idx, cand_cnt);
  }

  hipLaunchKernelGGL(finalize2_kernel, dim3(B_SZ), dim3(256), 0, stream,
                     x, W_enc, b_enc, cand_idx, cand_cnt, efail,
                     WdT, W_dec, acts, recon, useT, 0);
}